// Round 1
// baseline (211.384 us; speedup 1.0000x reference)
//
#include <hip/hip_runtime.h>
#include <math.h>

#define B_   2
#define C_   128
#define S_   64
#define H_   128
#define W_   512
#define M_   (S_ * S_)   // 4096
#define MID_ 32
#define EPS_ 1e-5f

// ---------------------------------------------------------------------------
// Kernel 1: k_w[b, w, h, :] = LN(grd_x[b, :, h, w]) @ wk + bk   for ALL w
// (k depends on m only through u[b,m], so precompute per unique w index)
// LN folded into matvec: LN(x)@wk = rstd*(sum_c x_c*g_c*wk[c,:] - m*gw) + bw
// ---------------------------------------------------------------------------
__global__ __launch_bounds__(256) void k_proj_kernel(
    const float* __restrict__ grd_x,   // [B, C, H, W]
    const float* __restrict__ ln_g,    // [C]
    const float* __restrict__ ln_b,    // [C]
    const float* __restrict__ wk,      // [C, MID]
    const float* __restrict__ bk,      // [MID]
    float* __restrict__ kw)            // [B, W, H, MID]
{
    __shared__ float4 wk4[C_ * MID_ / 4];   // 16 KB
    __shared__ float  gs[C_], bs[C_];
    __shared__ float  gw[MID_], bw[MID_];

    const int tid = threadIdx.x;
    const float4* wkg = (const float4*)wk;
    for (int i = tid; i < C_ * MID_ / 4; i += 256) wk4[i] = wkg[i];
    if (tid < C_) { gs[tid] = ln_g[tid]; bs[tid] = ln_b[tid]; }
    __syncthreads();

    if (tid < MID_) {
        float a = 0.f, c2 = 0.f;
        const float* wkf = (const float*)wk4;
        for (int c = 0; c < C_; ++c) {
            float wv = wkf[c * MID_ + tid];
            a  += gs[c] * wv;
            c2 += bs[c] * wv;
        }
        gw[tid] = a;
        bw[tid] = c2 + bk[tid];
    }
    __syncthreads();

    // grid = B * H * (W/256) = 2*128*2 = 512 blocks
    const int blk    = blockIdx.x;
    const int wchunk = blk & 1;
    const int h      = (blk >> 1) & (H_ - 1);
    const int b      = blk >> 8;
    const int w      = wchunk * 256 + tid;

    float s1 = 0.f, s2 = 0.f;
    float4 acc[8];
#pragma unroll
    for (int j = 0; j < 8; ++j) acc[j] = make_float4(0.f, 0.f, 0.f, 0.f);

    const float* gx = grd_x + ((size_t)b * C_ * H_ + h) * W_ + w;
#pragma unroll 4
    for (int c = 0; c < C_; ++c) {
        float x = gx[(size_t)c * H_ * W_];   // coalesced over w across lanes
        s1 += x;
        s2 += x * x;
        float xg = x * gs[c];
#pragma unroll
        for (int j = 0; j < 8; ++j) {
            float4 wr = wk4[c * 8 + j];      // LDS broadcast (same addr all lanes)
            acc[j].x += xg * wr.x;
            acc[j].y += xg * wr.y;
            acc[j].z += xg * wr.z;
            acc[j].w += xg * wr.w;
        }
    }

    const float mean = s1 * (1.f / C_);
    const float var  = s2 * (1.f / C_) - mean * mean;
    const float rstd = rsqrtf(var + EPS_);

    float4* outp = (float4*)(kw + (((size_t)b * W_ + w) * H_ + h) * MID_);
#pragma unroll
    for (int j = 0; j < 8; ++j) {
        float4 o;
        o.x = rstd * (acc[j].x - mean * gw[j * 4 + 0]) + bw[j * 4 + 0];
        o.y = rstd * (acc[j].y - mean * gw[j * 4 + 1]) + bw[j * 4 + 1];
        o.z = rstd * (acc[j].z - mean * gw[j * 4 + 2]) + bw[j * 4 + 2];
        o.w = rstd * (acc[j].w - mean * gw[j * 4 + 3]) + bw[j * 4 + 3];
        outp[j] = o;
    }
}

// ---------------------------------------------------------------------------
// Kernel 2: q[b, m, :] = LN(sat_x[b, :, m]) @ wq + bq  (same folded-LN trick)
// ---------------------------------------------------------------------------
__global__ __launch_bounds__(256) void q_proj_kernel(
    const float* __restrict__ sat_x,   // [B, C, M]
    const float* __restrict__ ln_g,
    const float* __restrict__ ln_b,
    const float* __restrict__ wq,      // [C, MID]
    const float* __restrict__ bq,      // [MID]
    float* __restrict__ q)             // [B, M, MID]
{
    __shared__ float4 wq4[C_ * MID_ / 4];
    __shared__ float  gs[C_], bs[C_];
    __shared__ float  gw[MID_], bw[MID_];

    const int tid = threadIdx.x;
    const float4* wqg = (const float4*)wq;
    for (int i = tid; i < C_ * MID_ / 4; i += 256) wq4[i] = wqg[i];
    if (tid < C_) { gs[tid] = ln_g[tid]; bs[tid] = ln_b[tid]; }
    __syncthreads();

    if (tid < MID_) {
        float a = 0.f, c2 = 0.f;
        const float* wqf = (const float*)wq4;
        for (int c = 0; c < C_; ++c) {
            float wv = wqf[c * MID_ + tid];
            a  += gs[c] * wv;
            c2 += bs[c] * wv;
        }
        gw[tid] = a;
        bw[tid] = c2 + bq[tid];
    }
    __syncthreads();

    // grid = B * (M/256) = 32 blocks
    const int blk    = blockIdx.x;
    const int mchunk = blk & 15;
    const int b      = blk >> 4;
    const int m      = mchunk * 256 + tid;

    float s1 = 0.f, s2 = 0.f;
    float4 acc[8];
#pragma unroll
    for (int j = 0; j < 8; ++j) acc[j] = make_float4(0.f, 0.f, 0.f, 0.f);

    const float* sx = sat_x + (size_t)b * C_ * M_ + m;
#pragma unroll 4
    for (int c = 0; c < C_; ++c) {
        float x = sx[(size_t)c * M_];
        s1 += x;
        s2 += x * x;
        float xg = x * gs[c];
#pragma unroll
        for (int j = 0; j < 8; ++j) {
            float4 wr = wq4[c * 8 + j];
            acc[j].x += xg * wr.x;
            acc[j].y += xg * wr.y;
            acc[j].z += xg * wr.z;
            acc[j].w += xg * wr.w;
        }
    }

    const float mean = s1 * (1.f / C_);
    const float var  = s2 * (1.f / C_) - mean * mean;
    const float rstd = rsqrtf(var + EPS_);

    float4* outp = (float4*)(q + ((size_t)b * M_ + m) * MID_);
#pragma unroll
    for (int j = 0; j < 8; ++j) {
        float4 o;
        o.x = rstd * (acc[j].x - mean * gw[j * 4 + 0]) + bw[j * 4 + 0];
        o.y = rstd * (acc[j].y - mean * gw[j * 4 + 1]) + bw[j * 4 + 1];
        o.z = rstd * (acc[j].z - mean * gw[j * 4 + 2]) + bw[j * 4 + 2];
        o.w = rstd * (acc[j].w - mean * gw[j * 4 + 3]) + bw[j * 4 + 3];
        outp[j] = o;
    }
}

// ---------------------------------------------------------------------------
// Kernel 3: per (b,m): dot over heads, softmax over H, weighted sum of v.
// One block of 128 threads (= H) per (b,m).
// ---------------------------------------------------------------------------
__global__ __launch_bounds__(128) void attn_kernel(
    const float* __restrict__ q,          // [B, M, MID]
    const float* __restrict__ kw,         // [B, W, H, MID]
    const float* __restrict__ grd_height, // [B, 1, H, W]
    const int*   __restrict__ u,          // [B, M]
    float* __restrict__ out)              // [B, M]
{
    const int h  = threadIdx.x;
    const int bm = blockIdx.x;            // b*M + m
    const int b  = bm >> 12;              // M = 4096

    __shared__ float qs[MID_];
    __shared__ float red[128];

    int uu = u[bm];
    uu = min(max(uu, 0), W_ - 1);

    if (h < MID_) qs[h] = q[(size_t)bm * MID_ + h];
    __syncthreads();

    const float4* kp = (const float4*)(kw + (((size_t)b * W_ + uu) * H_ + h) * MID_);
    float dot = 0.f;
#pragma unroll
    for (int j = 0; j < 8; ++j) {
        float4 kr = kp[j];
        dot += qs[j * 4 + 0] * kr.x + qs[j * 4 + 1] * kr.y
             + qs[j * 4 + 2] * kr.z + qs[j * 4 + 3] * kr.w;
    }
    dot *= 0.17677669529663687f;          // 32^-0.5

    // block softmax over 128 heads
    red[h] = dot;
    __syncthreads();
    for (int s = 64; s > 0; s >>= 1) {
        if (h < s) red[h] = fmaxf(red[h], red[h + s]);
        __syncthreads();
    }
    const float mx = red[0];
    __syncthreads();

    const float e = __expf(dot - mx);
    const float v = grd_height[((size_t)b * H_ + h) * W_ + uu];

    red[h] = e;
    __syncthreads();
    for (int s = 64; s > 0; s >>= 1) {
        if (h < s) red[h] += red[h + s];
        __syncthreads();
    }
    const float denom = red[0];
    __syncthreads();

    red[h] = e * v;
    __syncthreads();
    for (int s = 64; s > 0; s >>= 1) {
        if (h < s) red[h] += red[h + s];
        __syncthreads();
    }

    if (h == 0) out[bm] = red[0] / denom;
}

// ---------------------------------------------------------------------------
extern "C" void kernel_launch(void* const* d_in, const int* in_sizes, int n_in,
                              void* d_out, int out_size, void* d_ws, size_t ws_size,
                              hipStream_t stream) {
    const float* sat_x      = (const float*)d_in[0];
    const float* grd_x      = (const float*)d_in[1];
    const float* grd_height = (const float*)d_in[2];
    const int*   u          = (const int*)d_in[3];
    const float* ln_q_g     = (const float*)d_in[4];
    const float* ln_q_b     = (const float*)d_in[5];
    const float* wq         = (const float*)d_in[6];
    const float* bq         = (const float*)d_in[7];
    const float* ln_k_g     = (const float*)d_in[8];
    const float* ln_k_b     = (const float*)d_in[9];
    const float* wk         = (const float*)d_in[10];
    const float* bk         = (const float*)d_in[11];

    float* out = (float*)d_out;

    // workspace: kw = 16 MB, q = 1 MB
    float* kw = (float*)d_ws;
    float* q  = (float*)((char*)d_ws + (size_t)B_ * W_ * H_ * MID_ * sizeof(float));

    k_proj_kernel<<<B_ * H_ * (W_ / 256), 256, 0, stream>>>(
        grd_x, ln_k_g, ln_k_b, wk, bk, kw);
    q_proj_kernel<<<B_ * (M_ / 256), 256, 0, stream>>>(
        sat_x, ln_q_g, ln_q_b, wq, bq, q);
    attn_kernel<<<B_ * M_, 128, 0, stream>>>(
        q, kw, grd_height, u, out);
}

// Round 2
// 167.513 us; speedup vs baseline: 1.2619x; 1.2619x over previous
//
#include <hip/hip_runtime.h>
#include <math.h>

#define B_   2
#define C_   128
#define S_   64
#define H_   128
#define W_   512
#define M_   (S_ * S_)   // 4096
#define MID_ 32
#define EPS_ 1e-5f

#define KBLOCKS (B_ * H_ * (W_ / 256))   // 512
#define QBLOCKS (B_ * (M_ / 256))        // 32

// ---------------------------------------------------------------------------
// Merged projection kernel.
// Blocks [0, KBLOCKS):        k_w[b,w,h,:] = LN(grd_x[b,:,h,w]) @ wk + bk
// Blocks [KBLOCKS, +QBLOCKS): q[b,m,:]    = LN(sat_x[b,:,m])   @ wq + bq
//
// LN folded: LN(x)@W = rstd*(sum_c x_c*g_c*W[c,:] - mean*gw) + (b@W + bias)
// Weights are wave-uniform -> read with uniform indices so the compiler
// emits s_load (SMEM pipe) and v_fma with SGPR operands. NO LDS in the
// hot loop (R1 showed the LDS broadcast pipe was the serializer).
// ---------------------------------------------------------------------------
__global__ __launch_bounds__(256) void proj_kernel(
    const float* __restrict__ grd_x,   // [B, C, H, W]
    const float* __restrict__ sat_x,   // [B, C, M]
    const float* __restrict__ ln_k_g, const float* __restrict__ ln_k_b,
    const float* __restrict__ wk, const float* __restrict__ bk,
    const float* __restrict__ ln_q_g, const float* __restrict__ ln_q_b,
    const float* __restrict__ wq, const float* __restrict__ bq,
    float* __restrict__ kw,            // [B, W, H, MID]
    float* __restrict__ qv)            // [B, M, MID]
{
    const int tid = threadIdx.x;
    const int blk = blockIdx.x;
    const bool is_k = (blk < KBLOCKS);

    // Select operands (block-uniform branch)
    const float* g    = is_k ? ln_k_g : ln_q_g;
    const float* bln  = is_k ? ln_k_b : ln_q_b;
    const float* w    = is_k ? wk     : wq;
    const float* bias = is_k ? bk     : bq;

    const float* xptr;
    size_t       xstride;
    float*       outp;
    if (is_k) {
        const int wchunk = blk & 1;
        const int h      = (blk >> 1) & (H_ - 1);
        const int b      = blk >> 8;
        const int wpos   = wchunk * 256 + tid;
        xptr    = grd_x + ((size_t)b * C_ * H_ + h) * W_ + wpos;
        xstride = (size_t)H_ * W_;
        outp    = kw + (((size_t)b * W_ + wpos) * H_ + h) * MID_;
    } else {
        const int qblk = blk - KBLOCKS;
        const int b    = qblk >> 4;
        const int m    = (qblk & 15) * 256 + tid;
        xptr    = sat_x + (size_t)b * C_ * M_ + m;
        xstride = (size_t)M_;
        outp    = qv + ((size_t)b * M_ + m) * MID_;
    }

    // Per-block precompute of gw = g@W, bw = b@W + bias (32 threads, once)
    __shared__ float gwS[MID_], bwS[MID_];
    if (tid < MID_) {
        float a = 0.f, c2 = 0.f;
#pragma unroll 8
        for (int c = 0; c < C_; ++c) {
            float wv = w[c * MID_ + tid];   // coalesced vector load, once per block
            a  = fmaf(g[c],   wv, a);
            c2 = fmaf(bln[c], wv, c2);
        }
        gwS[tid] = a;
        bwS[tid] = c2 + bias[tid];
    }
    __syncthreads();

    // Main loop: one x element per c (coalesced), weights via scalar loads.
    float acc[MID_];
#pragma unroll
    for (int j = 0; j < MID_; ++j) acc[j] = 0.f;
    float s1 = 0.f, s2 = 0.f;

    for (int c0 = 0; c0 < C_; c0 += 8) {
        float xv[8];
#pragma unroll
        for (int i = 0; i < 8; ++i)          // 8 independent HBM loads in flight
            xv[i] = xptr[(size_t)(c0 + i) * xstride];
#pragma unroll
        for (int i = 0; i < 8; ++i) {
            const int   c  = c0 + i;
            const float x  = xv[i];
            s1 += x;
            s2  = fmaf(x, x, s2);
            const float xg = x * g[c];       // g[c]: uniform -> SGPR
            const float* wr = w + c * MID_;  // uniform row -> s_load_dwordx16
#pragma unroll
            for (int j = 0; j < MID_; ++j)
                acc[j] = fmaf(xg, wr[j], acc[j]);
        }
    }

    const float mean = s1 * (1.f / C_);
    const float var  = fmaf(-mean, mean, s2 * (1.f / C_));
    const float rstd = rsqrtf(var + EPS_);

    float4* op = (float4*)outp;
#pragma unroll
    for (int j4 = 0; j4 < MID_ / 4; ++j4) {
        float4 o;
        o.x = fmaf(rstd, acc[j4 * 4 + 0] - mean * gwS[j4 * 4 + 0], bwS[j4 * 4 + 0]);
        o.y = fmaf(rstd, acc[j4 * 4 + 1] - mean * gwS[j4 * 4 + 1], bwS[j4 * 4 + 1]);
        o.z = fmaf(rstd, acc[j4 * 4 + 2] - mean * gwS[j4 * 4 + 2], bwS[j4 * 4 + 2]);
        o.w = fmaf(rstd, acc[j4 * 4 + 3] - mean * gwS[j4 * 4 + 3], bwS[j4 * 4 + 3]);
        op[j4] = o;
    }
}

// ---------------------------------------------------------------------------
// Attention: block = (b,m), 128 threads (= heads). Shuffle reductions.
// ---------------------------------------------------------------------------
__global__ __launch_bounds__(128) void attn_kernel(
    const float* __restrict__ q,          // [B, M, MID]
    const float* __restrict__ kwt,        // [B, W, H, MID]
    const float* __restrict__ grd_height, // [B, 1, H, W]
    const int*   __restrict__ u,          // [B, M]
    float* __restrict__ out)              // [B, M]
{
    const int h  = threadIdx.x;
    const int bm = blockIdx.x;
    const int b  = bm >> 12;              // M = 4096

    __shared__ float qs[MID_];
    __shared__ float smax[2], ssum[2], ssumv[2];

    int uu = u[bm];
    uu = min(max(uu, 0), W_ - 1);

    if (h < MID_) qs[h] = q[(size_t)bm * MID_ + h];
    __syncthreads();

    const float4* kp = (const float4*)(kwt + (((size_t)b * W_ + uu) * H_ + h) * MID_);
    float dot = 0.f;
#pragma unroll
    for (int j = 0; j < 8; ++j) {
        float4 kr = kp[j];
        dot = fmaf(qs[j * 4 + 0], kr.x, dot);
        dot = fmaf(qs[j * 4 + 1], kr.y, dot);
        dot = fmaf(qs[j * 4 + 2], kr.z, dot);
        dot = fmaf(qs[j * 4 + 3], kr.w, dot);
    }
    dot *= 0.17677669529663687f;          // 32^-0.5

    // wave max (width 64) + cross-wave combine
    float mx = dot;
#pragma unroll
    for (int o = 32; o > 0; o >>= 1) mx = fmaxf(mx, __shfl_xor(mx, o, 64));
    if ((h & 63) == 0) smax[h >> 6] = mx;
    __syncthreads();
    mx = fmaxf(smax[0], smax[1]);

    const float v  = grd_height[((size_t)b * H_ + h) * W_ + uu];
    float e  = __expf(dot - mx);
    float ev = e * v;
#pragma unroll
    for (int o = 32; o > 0; o >>= 1) {
        e  += __shfl_xor(e,  o, 64);
        ev += __shfl_xor(ev, o, 64);
    }
    if ((h & 63) == 0) { ssum[h >> 6] = e; ssumv[h >> 6] = ev; }
    __syncthreads();

    if (h == 0) out[bm] = (ssumv[0] + ssumv[1]) / (ssum[0] + ssum[1]);
}

// ---------------------------------------------------------------------------
extern "C" void kernel_launch(void* const* d_in, const int* in_sizes, int n_in,
                              void* d_out, int out_size, void* d_ws, size_t ws_size,
                              hipStream_t stream) {
    const float* sat_x      = (const float*)d_in[0];
    const float* grd_x      = (const float*)d_in[1];
    const float* grd_height = (const float*)d_in[2];
    const int*   u          = (const int*)d_in[3];
    const float* ln_q_g     = (const float*)d_in[4];
    const float* ln_q_b     = (const float*)d_in[5];
    const float* wq         = (const float*)d_in[6];
    const float* bq         = (const float*)d_in[7];
    const float* ln_k_g     = (const float*)d_in[8];
    const float* ln_k_b     = (const float*)d_in[9];
    const float* wk         = (const float*)d_in[10];
    const float* bk         = (const float*)d_in[11];

    float* out = (float*)d_out;

    // workspace: kw = 16 MB, q = 1 MB
    float* kw = (float*)d_ws;
    float* q  = (float*)((char*)d_ws + (size_t)B_ * W_ * H_ * MID_ * sizeof(float));

    proj_kernel<<<KBLOCKS + QBLOCKS, 256, 0, stream>>>(
        grd_x, sat_x, ln_k_g, ln_k_b, wk, bk, ln_q_g, ln_q_b, wq, bq, kw, q);
    attn_kernel<<<B_ * M_, 128, 0, stream>>>(
        q, kw, grd_height, u, out);
}

// Round 3
// 165.409 us; speedup vs baseline: 1.2779x; 1.0127x over previous
//
#include <hip/hip_runtime.h>
#include <math.h>

#define B_   2
#define C_   128
#define S_   64
#define H_   128
#define W_   512
#define M_   (S_ * S_)   // 4096
#define MID_ 32
#define EPS_ 1e-5f

#define KB3 (B_ * H_ * (W_ / 64))   // 2048 k-blocks (64 w-positions each)
#define QB3 (B_ * (M_ / 64))        // 128 q-blocks  (64 m-positions each)

// ---------------------------------------------------------------------------
// Projection, split-C over 4 waves.
// Block = 256 threads = 4 waves; wave wv owns c-chunk [wv*32, wv*32+32),
// lanes = 64 output positions. c is wave-uniform -> weights via s_load.
// Cross-wave reduction of acc[32] through swizzled LDS in two 16-j halves.
// ---------------------------------------------------------------------------
__global__ __launch_bounds__(256) void proj_kernel(
    const float* __restrict__ grd_x,   // [B, C, H, W]
    const float* __restrict__ sat_x,   // [B, C, M]
    const float* __restrict__ ln_k_g, const float* __restrict__ ln_k_b,
    const float* __restrict__ wk, const float* __restrict__ bk,
    const float* __restrict__ ln_q_g, const float* __restrict__ ln_q_b,
    const float* __restrict__ wq, const float* __restrict__ bq,
    float* __restrict__ kw,            // [B, W, H, MID]
    float* __restrict__ qv)            // [B, M, MID]
{
    __shared__ float4 accS[4][64][4];       // 16 KB, f4-swizzled half-buffer
    __shared__ float2 sAB[4][64];           // 2 KB  (s1, s2 partials)
    __shared__ float  gwP[8][32], bwP[8][32];
    __shared__ float  gwS[MID_], bwS[MID_];
    __shared__ float  msS[64], rsS[64];

    const int tid  = threadIdx.x;
    const int lane = tid & 63;
    const int wv   = __builtin_amdgcn_readfirstlane(tid >> 6);  // wave-uniform
    const int blk  = blockIdx.x;
    const bool is_k = (blk < KB3);

    const float* gl   = is_k ? ln_k_g : ln_q_g;
    const float* bl   = is_k ? ln_k_b : ln_q_b;
    const float* wt   = is_k ? wk     : wq;
    const float* bias = is_k ? bk     : bq;

    // geometry
    int b, h = 0, pos0;
    const float* xbase;
    size_t xstr;
    if (is_k) {
        const int wchunk = blk & 7;
        h    = (blk >> 3) & (H_ - 1);
        b    = blk >> 10;
        pos0 = wchunk * 64;
        xbase = grd_x + (size_t)b * C_ * H_ * W_ + (size_t)h * W_ + pos0 + lane;
        xstr  = (size_t)H_ * W_;
    } else {
        const int qblk = blk - KB3;
        b    = qblk >> 6;
        pos0 = (qblk & 63) * 64;
        xbase = sat_x + (size_t)b * C_ * M_ + pos0 + lane;
        xstr  = (size_t)M_;
    }

    // ---- gw/bw partials (g@W, b@W), split 8 ways over c ----
    {
        const int j  = tid & 31;
        const int ch = tid >> 5;                  // 0..7, 16 c's each
        const float* wp = wt + (size_t)(ch * 16) * MID_ + j;
        float a = 0.f, c2 = 0.f;
#pragma unroll
        for (int i = 0; i < 16; ++i) {
            const float wvv = wp[(size_t)i * MID_];
            a  = fmaf(gl[ch * 16 + i], wvv, a);
            c2 = fmaf(bl[ch * 16 + i], wvv, c2);
        }
        gwP[ch][j] = a;
        bwP[ch][j] = c2;
    }

    // ---- main loop: 32 c's, software-pipelined x loads ----
    const float* xp   = xbase + (size_t)(wv * 32) * xstr;
    const float* wrow = wt + (size_t)(wv * 32) * MID_;    // wave-uniform
    const float* grow = gl + wv * 32;                     // wave-uniform

    float acc[MID_];
#pragma unroll
    for (int j = 0; j < MID_; ++j) acc[j] = 0.f;
    float s1 = 0.f, s2 = 0.f;

    float xv[2][8];
#pragma unroll
    for (int i = 0; i < 8; ++i) xv[0][i] = xp[(size_t)i * xstr];

    for (int g = 0; g < 4; ++g) {
        if (g < 3) {
#pragma unroll
            for (int i = 0; i < 8; ++i)
                xv[(g + 1) & 1][i] = xp[(size_t)((g + 1) * 8 + i) * xstr];
        }
#pragma unroll
        for (int i = 0; i < 8; ++i) {
            const int   cl = g * 8 + i;
            const float x  = xv[g & 1][i];
            s1 += x;
            s2  = fmaf(x, x, s2);
            const float xg = x * grow[cl];       // uniform -> SGPR
            const float* wr = wrow + cl * MID_;  // uniform row -> s_load
#pragma unroll
            for (int j = 0; j < MID_; ++j)
                acc[j] = fmaf(xg, wr[j], acc[j]);
        }
    }

    // ---- stage partials: s1/s2 + acc half 0 (j 0..15) ----
    sAB[wv][lane] = make_float2(s1, s2);
#pragma unroll
    for (int j4 = 0; j4 < 4; ++j4)
        accS[wv][lane][(j4 + lane) & 3] =
            make_float4(acc[j4 * 4 + 0], acc[j4 * 4 + 1],
                        acc[j4 * 4 + 2], acc[j4 * 4 + 3]);
    __syncthreads();

    // ---- finalize mean/rstd and gw/bw (disjoint thread groups) ----
    if (tid < 64) {
        float a = 0.f, c2 = 0.f;
#pragma unroll
        for (int w2 = 0; w2 < 4; ++w2) { a += sAB[w2][tid].x; c2 += sAB[w2][tid].y; }
        const float mean = a * (1.f / C_);
        const float var  = fmaf(-mean, mean, c2 * (1.f / C_));
        msS[tid] = mean;
        rsS[tid] = rsqrtf(var + EPS_);
    } else if (tid < 96) {
        const int j = tid - 64;
        float a = 0.f;
#pragma unroll
        for (int ch = 0; ch < 8; ++ch) a += gwP[ch][j];
        gwS[j] = a;
    } else if (tid < 128) {
        const int j = tid - 96;
        float a = 0.f;
#pragma unroll
        for (int ch = 0; ch < 8; ++ch) a += bwP[ch][j];
        bwS[j] = a + bias[j];
    }
    __syncthreads();

    // ---- reduce + LN + store, phase 0 (j 0..15) ----
    const int pos = tid >> 2;
    const int jq  = tid & 3;
    float* orow;
    if (is_k) orow = kw + (((size_t)b * W_ + pos0 + pos) * H_ + h) * MID_;
    else      orow = qv + ((size_t)(b << 12) + pos0 + pos) * MID_;
    const float mean = msS[pos];
    const float rstd = rsS[pos];

    {
        float4 r = accS[0][pos][(jq + pos) & 3];
#pragma unroll
        for (int w2 = 1; w2 < 4; ++w2) {
            const float4 t = accS[w2][pos][(jq + pos) & 3];
            r.x += t.x; r.y += t.y; r.z += t.z; r.w += t.w;
        }
        const int j0 = jq * 4;
        float4 o;
        o.x = fmaf(rstd, r.x - mean * gwS[j0 + 0], bwS[j0 + 0]);
        o.y = fmaf(rstd, r.y - mean * gwS[j0 + 1], bwS[j0 + 1]);
        o.z = fmaf(rstd, r.z - mean * gwS[j0 + 2], bwS[j0 + 2]);
        o.w = fmaf(rstd, r.w - mean * gwS[j0 + 3], bwS[j0 + 3]);
        *(float4*)(orow + j0) = o;
    }
    __syncthreads();

    // ---- stage acc half 1 (j 16..31) ----
#pragma unroll
    for (int j4 = 0; j4 < 4; ++j4)
        accS[wv][lane][(j4 + lane) & 3] =
            make_float4(acc[16 + j4 * 4 + 0], acc[16 + j4 * 4 + 1],
                        acc[16 + j4 * 4 + 2], acc[16 + j4 * 4 + 3]);
    __syncthreads();

    {
        float4 r = accS[0][pos][(jq + pos) & 3];
#pragma unroll
        for (int w2 = 1; w2 < 4; ++w2) {
            const float4 t = accS[w2][pos][(jq + pos) & 3];
            r.x += t.x; r.y += t.y; r.z += t.z; r.w += t.w;
        }
        const int j0 = 16 + jq * 4;
        float4 o;
        o.x = fmaf(rstd, r.x - mean * gwS[j0 + 0], bwS[j0 + 0]);
        o.y = fmaf(rstd, r.y - mean * gwS[j0 + 1], bwS[j0 + 1]);
        o.z = fmaf(rstd, r.z - mean * gwS[j0 + 2], bwS[j0 + 2]);
        o.w = fmaf(rstd, r.w - mean * gwS[j0 + 3], bwS[j0 + 3]);
        *(float4*)(orow + j0) = o;
    }
}

// ---------------------------------------------------------------------------
// Attention: ONE WAVE per (b,m). lane owns heads (lane, lane+64).
// bm is wave-uniform -> u and q row via scalar loads. No LDS, no barriers.
// ---------------------------------------------------------------------------
__global__ __launch_bounds__(256) void attn_kernel(
    const float* __restrict__ q,          // [B, M, MID]
    const float* __restrict__ kwt,        // [B, W, H, MID]
    const float* __restrict__ grd_height, // [B, 1, H, W]
    const int*   __restrict__ u,          // [B, M]
    float* __restrict__ out)              // [B, M]
{
    const int tid  = threadIdx.x;
    const int lane = tid & 63;
    const int wv   = __builtin_amdgcn_readfirstlane(tid >> 6);
    const int bm   = blockIdx.x * 4 + wv;            // wave-uniform
    const int b    = bm >> 12;                       // M = 4096

    int uu = u[bm];                                  // uniform -> s_load
    uu = min(max(uu, 0), W_ - 1);

    // q row: uniform address -> s_load_dwordx16 x2
    const float* qr = q + (size_t)bm * MID_;
    float sq[MID_];
#pragma unroll
    for (int j = 0; j < MID_; ++j) sq[j] = qr[j];

    const float4* k4 = (const float4*)(kwt + ((size_t)b * W_ + uu) * H_ * MID_);
    float4 ka[8], kb[8];
#pragma unroll
    for (int j = 0; j < 8; ++j) ka[j] = k4[(size_t)lane * 8 + j];
#pragma unroll
    for (int j = 0; j < 8; ++j) kb[j] = k4[(size_t)(lane + 64) * 8 + j];

    float d0 = 0.f, d1 = 0.f;
#pragma unroll
    for (int j = 0; j < 8; ++j) {
        d0 = fmaf(sq[j * 4 + 0], ka[j].x, d0);
        d0 = fmaf(sq[j * 4 + 1], ka[j].y, d0);
        d0 = fmaf(sq[j * 4 + 2], ka[j].z, d0);
        d0 = fmaf(sq[j * 4 + 3], ka[j].w, d0);
        d1 = fmaf(sq[j * 4 + 0], kb[j].x, d1);
        d1 = fmaf(sq[j * 4 + 1], kb[j].y, d1);
        d1 = fmaf(sq[j * 4 + 2], kb[j].z, d1);
        d1 = fmaf(sq[j * 4 + 3], kb[j].w, d1);
    }
    const float sc = 0.17677669529663687f;           // 32^-0.5
    d0 *= sc; d1 *= sc;

    float mx = fmaxf(d0, d1);
#pragma unroll
    for (int o = 32; o > 0; o >>= 1) mx = fmaxf(mx, __shfl_xor(mx, o, 64));

    const float v0 = grd_height[((size_t)b * H_ + lane) * W_ + uu];
    const float v1 = grd_height[((size_t)b * H_ + lane + 64) * W_ + uu];
    float e0 = __expf(d0 - mx);
    float e1 = __expf(d1 - mx);
    float s  = e0 + e1;
    float svv = fmaf(e0, v0, e1 * v1);
#pragma unroll
    for (int o = 32; o > 0; o >>= 1) {
        s   += __shfl_xor(s,   o, 64);
        svv += __shfl_xor(svv, o, 64);
    }

    if (lane == 0) out[bm] = svv / s;
}

// ---------------------------------------------------------------------------
extern "C" void kernel_launch(void* const* d_in, const int* in_sizes, int n_in,
                              void* d_out, int out_size, void* d_ws, size_t ws_size,
                              hipStream_t stream) {
    const float* sat_x      = (const float*)d_in[0];
    const float* grd_x      = (const float*)d_in[1];
    const float* grd_height = (const float*)d_in[2];
    const int*   u          = (const int*)d_in[3];
    const float* ln_q_g     = (const float*)d_in[4];
    const float* ln_q_b     = (const float*)d_in[5];
    const float* wq         = (const float*)d_in[6];
    const float* bq         = (const float*)d_in[7];
    const float* ln_k_g     = (const float*)d_in[8];
    const float* ln_k_b     = (const float*)d_in[9];
    const float* wk         = (const float*)d_in[10];
    const float* bk         = (const float*)d_in[11];

    float* out = (float*)d_out;

    // workspace: kw = 16 MB, q = 1 MB
    float* kw = (float*)d_ws;
    float* q  = (float*)((char*)d_ws + (size_t)B_ * W_ * H_ * MID_ * sizeof(float));

    proj_kernel<<<KB3 + QB3, 256, 0, stream>>>(
        grd_x, sat_x, ln_k_g, ln_k_b, wk, bk, ln_q_g, ln_q_b, wq, bq, kw, q);
    attn_kernel<<<(B_ * M_) / 4, 256, 0, stream>>>(
        q, kw, grd_height, u, out);
}

// Round 4
// 153.851 us; speedup vs baseline: 1.3740x; 1.0751x over previous
//
#include <hip/hip_runtime.h>
#include <math.h>

#define B_   2
#define C_   128
#define S_   64
#define H_   128
#define W_   512
#define M_   (S_ * S_)   // 4096
#define MID_ 32
#define EPS_ 1e-5f
#define CAP_ 192         // bucket capacity; E[n]=8 (Poisson), overflow ~impossible

#define KB3 (B_ * H_ * (W_ / 64))   // 2048 k-blocks (64 w-positions each)
#define QB3 (B_ * (M_ / 64))        // 128 q-blocks  (64 m-positions each)

// ---------------------------------------------------------------------------
// Projection, split-C over 4 waves (UNCHANGED from R3 — clean A/B vs attn).
// ---------------------------------------------------------------------------
__global__ __launch_bounds__(256) void proj_kernel(
    const float* __restrict__ grd_x,   // [B, C, H, W]
    const float* __restrict__ sat_x,   // [B, C, M]
    const float* __restrict__ ln_k_g, const float* __restrict__ ln_k_b,
    const float* __restrict__ wk, const float* __restrict__ bk,
    const float* __restrict__ ln_q_g, const float* __restrict__ ln_q_b,
    const float* __restrict__ wq, const float* __restrict__ bq,
    float* __restrict__ kw,            // [B, W, H, MID]
    float* __restrict__ qv)            // [B, M, MID]
{
    __shared__ float4 accS[4][64][4];       // 16 KB, f4-swizzled half-buffer
    __shared__ float2 sAB[4][64];           // 2 KB  (s1, s2 partials)
    __shared__ float  gwP[8][32], bwP[8][32];
    __shared__ float  gwS[MID_], bwS[MID_];
    __shared__ float  msS[64], rsS[64];

    const int tid  = threadIdx.x;
    const int lane = tid & 63;
    const int wv   = __builtin_amdgcn_readfirstlane(tid >> 6);  // wave-uniform
    const int blk  = blockIdx.x;
    const bool is_k = (blk < KB3);

    const float* gl   = is_k ? ln_k_g : ln_q_g;
    const float* bl   = is_k ? ln_k_b : ln_q_b;
    const float* wt   = is_k ? wk     : wq;
    const float* bias = is_k ? bk     : bq;

    // geometry
    int b, h = 0, pos0;
    const float* xbase;
    size_t xstr;
    if (is_k) {
        const int wchunk = blk & 7;
        h    = (blk >> 3) & (H_ - 1);
        b    = blk >> 10;
        pos0 = wchunk * 64;
        xbase = grd_x + (size_t)b * C_ * H_ * W_ + (size_t)h * W_ + pos0 + lane;
        xstr  = (size_t)H_ * W_;
    } else {
        const int qblk = blk - KB3;
        b    = qblk >> 6;
        pos0 = (qblk & 63) * 64;
        xbase = sat_x + (size_t)b * C_ * M_ + pos0 + lane;
        xstr  = (size_t)M_;
    }

    // ---- gw/bw partials (g@W, b@W), split 8 ways over c ----
    {
        const int j  = tid & 31;
        const int ch = tid >> 5;                  // 0..7, 16 c's each
        const float* wp = wt + (size_t)(ch * 16) * MID_ + j;
        float a = 0.f, c2 = 0.f;
#pragma unroll
        for (int i = 0; i < 16; ++i) {
            const float wvv = wp[(size_t)i * MID_];
            a  = fmaf(gl[ch * 16 + i], wvv, a);
            c2 = fmaf(bl[ch * 16 + i], wvv, c2);
        }
        gwP[ch][j] = a;
        bwP[ch][j] = c2;
    }

    // ---- main loop: 32 c's, software-pipelined x loads ----
    const float* xp   = xbase + (size_t)(wv * 32) * xstr;
    const float* wrow = wt + (size_t)(wv * 32) * MID_;    // wave-uniform
    const float* grow = gl + wv * 32;                     // wave-uniform

    float acc[MID_];
#pragma unroll
    for (int j = 0; j < MID_; ++j) acc[j] = 0.f;
    float s1 = 0.f, s2 = 0.f;

    float xv[2][8];
#pragma unroll
    for (int i = 0; i < 8; ++i) xv[0][i] = xp[(size_t)i * xstr];

    for (int g = 0; g < 4; ++g) {
        if (g < 3) {
#pragma unroll
            for (int i = 0; i < 8; ++i)
                xv[(g + 1) & 1][i] = xp[(size_t)((g + 1) * 8 + i) * xstr];
        }
#pragma unroll
        for (int i = 0; i < 8; ++i) {
            const int   cl = g * 8 + i;
            const float x  = xv[g & 1][i];
            s1 += x;
            s2  = fmaf(x, x, s2);
            const float xg = x * grow[cl];       // uniform -> SGPR
            const float* wr = wrow + cl * MID_;  // uniform row -> s_load
#pragma unroll
            for (int j = 0; j < MID_; ++j)
                acc[j] = fmaf(xg, wr[j], acc[j]);
        }
    }

    // ---- stage partials: s1/s2 + acc half 0 (j 0..15) ----
    sAB[wv][lane] = make_float2(s1, s2);
#pragma unroll
    for (int j4 = 0; j4 < 4; ++j4)
        accS[wv][lane][(j4 + lane) & 3] =
            make_float4(acc[j4 * 4 + 0], acc[j4 * 4 + 1],
                        acc[j4 * 4 + 2], acc[j4 * 4 + 3]);
    __syncthreads();

    // ---- finalize mean/rstd and gw/bw (disjoint thread groups) ----
    if (tid < 64) {
        float a = 0.f, c2 = 0.f;
#pragma unroll
        for (int w2 = 0; w2 < 4; ++w2) { a += sAB[w2][tid].x; c2 += sAB[w2][tid].y; }
        const float mean = a * (1.f / C_);
        const float var  = fmaf(-mean, mean, c2 * (1.f / C_));
        msS[tid] = mean;
        rsS[tid] = rsqrtf(var + EPS_);
    } else if (tid < 96) {
        const int j = tid - 64;
        float a = 0.f;
#pragma unroll
        for (int ch = 0; ch < 8; ++ch) a += gwP[ch][j];
        gwS[j] = a;
    } else if (tid < 128) {
        const int j = tid - 96;
        float a = 0.f;
#pragma unroll
        for (int ch = 0; ch < 8; ++ch) a += bwP[ch][j];
        bwS[j] = a + bias[j];
    }
    __syncthreads();

    // ---- reduce + LN + store, phase 0 (j 0..15) ----
    const int pos = tid >> 2;
    const int jq  = tid & 3;
    float* orow;
    if (is_k) orow = kw + (((size_t)b * W_ + pos0 + pos) * H_ + h) * MID_;
    else      orow = qv + ((size_t)(b << 12) + pos0 + pos) * MID_;
    const float mean = msS[pos];
    const float rstd = rsS[pos];

    {
        float4 r = accS[0][pos][(jq + pos) & 3];
#pragma unroll
        for (int w2 = 1; w2 < 4; ++w2) {
            const float4 t = accS[w2][pos][(jq + pos) & 3];
            r.x += t.x; r.y += t.y; r.z += t.z; r.w += t.w;
        }
        const int j0 = jq * 4;
        float4 o;
        o.x = fmaf(rstd, r.x - mean * gwS[j0 + 0], bwS[j0 + 0]);
        o.y = fmaf(rstd, r.y - mean * gwS[j0 + 1], bwS[j0 + 1]);
        o.z = fmaf(rstd, r.z - mean * gwS[j0 + 2], bwS[j0 + 2]);
        o.w = fmaf(rstd, r.w - mean * gwS[j0 + 3], bwS[j0 + 3]);
        *(float4*)(orow + j0) = o;
    }
    __syncthreads();

    // ---- stage acc half 1 (j 16..31) ----
#pragma unroll
    for (int j4 = 0; j4 < 4; ++j4)
        accS[wv][lane][(j4 + lane) & 3] =
            make_float4(acc[16 + j4 * 4 + 0], acc[16 + j4 * 4 + 1],
                        acc[16 + j4 * 4 + 2], acc[16 + j4 * 4 + 3]);
    __syncthreads();

    {
        float4 r = accS[0][pos][(jq + pos) & 3];
#pragma unroll
        for (int w2 = 1; w2 < 4; ++w2) {
            const float4 t = accS[w2][pos][(jq + pos) & 3];
            r.x += t.x; r.y += t.y; r.z += t.z; r.w += t.w;
        }
        const int j0 = 16 + jq * 4;
        float4 o;
        o.x = fmaf(rstd, r.x - mean * gwS[j0 + 0], bwS[j0 + 0]);
        o.y = fmaf(rstd, r.y - mean * gwS[j0 + 1], bwS[j0 + 1]);
        o.z = fmaf(rstd, r.z - mean * gwS[j0 + 2], bwS[j0 + 2]);
        o.w = fmaf(rstd, r.w - mean * gwS[j0 + 3], bwS[j0 + 3]);
        *(float4*)(orow + j0) = o;
    }
}

// ---------------------------------------------------------------------------
// Bucket build: counts[b][w]++, scatter bm into bucket[(b,w)][slot].
// Overflow (never in practice): compute this m inline via online softmax.
// ---------------------------------------------------------------------------
__global__ __launch_bounds__(256) void count_kernel(
    const int*   __restrict__ u,       // [B, M]
    const float* __restrict__ qv,      // [B, M, MID]  (fallback only)
    const float* __restrict__ kw,      // [B, W, H, MID] (fallback only)
    const float* __restrict__ gh,      // [B, 1, H, W]   (fallback only)
    int* __restrict__ counts,          // [B*W]
    int* __restrict__ bucket,          // [B*W][CAP_]
    float* __restrict__ out)           // [B, M]
{
    const int bm = blockIdx.x * 256 + threadIdx.x;   // 0..8191
    const int b  = bm >> 12;
    int w = u[bm];
    w = min(max(w, 0), W_ - 1);
    const int bw  = b * W_ + w;
    const int pos = atomicAdd(&counts[bw], 1);
    if (pos < CAP_) {
        bucket[bw * CAP_ + pos] = bm;
    } else {
        // dead in practice — online-softmax scalar fallback
        const float* qr = qv + (size_t)bm * MID_;
        const float* kr = kw + (size_t)bw * H_ * MID_;
        float mx = -1e30f, s = 0.f, sv = 0.f;
        for (int h = 0; h < H_; ++h) {
            float d = 0.f;
            for (int j = 0; j < MID_; ++j) d = fmaf(qr[j], kr[h * MID_ + j], d);
            d *= 0.17677669529663687f;
            const float nm   = fmaxf(mx, d);
            const float corr = __expf(mx - nm);
            const float e    = __expf(d - nm);
            s  = fmaf(s,  corr, e);
            sv = fmaf(sv, corr, e * gh[((size_t)b * H_ + h) * W_ + w]);
            mx = nm;
        }
        out[bm] = sv / s;
    }
}

// ---------------------------------------------------------------------------
// Bucketed attention: block per (b,w); each wave hoists its k fragment and
// v values ONCE, then loops over the bucket's m's (q via s_load + shuffles).
// kw traffic: 64 KB/block (was 16 KB per m) -> 256 MB -> 64 MB total.
// ---------------------------------------------------------------------------
__global__ __launch_bounds__(256) void battn_kernel(
    const float* __restrict__ qv,      // [B, M, MID]
    const float* __restrict__ kw,      // [B, W, H, MID]
    const float* __restrict__ gh,      // [B, 1, H, W]
    const int*   __restrict__ counts,  // [B*W]
    const int*   __restrict__ bucket,  // [B*W][CAP_]
    float* __restrict__ out)           // [B, M]
{
    const int blk = blockIdx.x;                      // b*W + w
    const int n   = min(counts[blk], CAP_);
    const int tid  = threadIdx.x;
    const int lane = tid & 63;
    const int wv   = __builtin_amdgcn_readfirstlane(tid >> 6);
    if (wv >= n) return;                             // wave-uniform exit

    const int b = blk >> 9;
    const int w = blk & (W_ - 1);

    const float4* k4 = (const float4*)(kw + (size_t)blk * H_ * MID_);
    float4 ka[8], kb[8];
#pragma unroll
    for (int j = 0; j < 8; ++j) ka[j] = k4[lane * 8 + j];
#pragma unroll
    for (int j = 0; j < 8; ++j) kb[j] = k4[(lane + 64) * 8 + j];

    const float v0 = gh[((size_t)b * H_ + lane) * W_ + w];
    const float v1 = gh[((size_t)b * H_ + lane + 64) * W_ + w];

    const int* bkt = bucket + (size_t)blk * CAP_;
    const float sc = 0.17677669529663687f;           // 32^-0.5

    for (int i = wv; i < n; i += 4) {
        const int bm = bkt[i];                       // wave-uniform -> s_load
        const float* qr = qv + (size_t)bm * MID_;    // uniform -> s_load
        float sq[MID_];
#pragma unroll
        for (int j = 0; j < MID_; ++j) sq[j] = qr[j];

        float d0 = 0.f, d1 = 0.f;
#pragma unroll
        for (int j = 0; j < 8; ++j) {
            d0 = fmaf(sq[j * 4 + 0], ka[j].x, d0);
            d0 = fmaf(sq[j * 4 + 1], ka[j].y, d0);
            d0 = fmaf(sq[j * 4 + 2], ka[j].z, d0);
            d0 = fmaf(sq[j * 4 + 3], ka[j].w, d0);
            d1 = fmaf(sq[j * 4 + 0], kb[j].x, d1);
            d1 = fmaf(sq[j * 4 + 1], kb[j].y, d1);
            d1 = fmaf(sq[j * 4 + 2], kb[j].z, d1);
            d1 = fmaf(sq[j * 4 + 3], kb[j].w, d1);
        }
        d0 *= sc; d1 *= sc;

        float mx = fmaxf(d0, d1);
#pragma unroll
        for (int o = 32; o > 0; o >>= 1) mx = fmaxf(mx, __shfl_xor(mx, o, 64));

        const float e0 = __expf(d0 - mx);
        const float e1 = __expf(d1 - mx);
        float s   = e0 + e1;
        float svv = fmaf(e0, v0, e1 * v1);
#pragma unroll
        for (int o = 32; o > 0; o >>= 1) {
            s   += __shfl_xor(s,   o, 64);
            svv += __shfl_xor(svv, o, 64);
        }

        if (lane == 0) out[bm] = svv / s;
    }
}

// ---------------------------------------------------------------------------
extern "C" void kernel_launch(void* const* d_in, const int* in_sizes, int n_in,
                              void* d_out, int out_size, void* d_ws, size_t ws_size,
                              hipStream_t stream) {
    const float* sat_x      = (const float*)d_in[0];
    const float* grd_x      = (const float*)d_in[1];
    const float* grd_height = (const float*)d_in[2];
    const int*   u          = (const int*)d_in[3];
    const float* ln_q_g     = (const float*)d_in[4];
    const float* ln_q_b     = (const float*)d_in[5];
    const float* wq         = (const float*)d_in[6];
    const float* bq         = (const float*)d_in[7];
    const float* ln_k_g     = (const float*)d_in[8];
    const float* ln_k_b     = (const float*)d_in[9];
    const float* wk         = (const float*)d_in[10];
    const float* bk         = (const float*)d_in[11];

    float* out = (float*)d_out;

    // workspace layout
    char* ws = (char*)d_ws;
    float* kw     = (float*)ws;                                   // 16 MB
    float* q      = (float*)(ws + (size_t)16 * 1024 * 1024);      // 1 MB
    int*   counts = (int*)  (ws + (size_t)17 * 1024 * 1024);      // 4 KB
    int*   bucket = counts + B_ * W_;                             // 768 KB

    hipMemsetAsync(counts, 0, B_ * W_ * sizeof(int), stream);

    proj_kernel<<<KB3 + QB3, 256, 0, stream>>>(
        grd_x, sat_x, ln_k_g, ln_k_b, wk, bk, ln_q_g, ln_q_b, wq, bq, kw, q);
    count_kernel<<<(B_ * M_) / 256, 256, 0, stream>>>(
        u, q, kw, grd_height, counts, bucket, out);
    battn_kernel<<<B_ * W_, 256, 0, stream>>>(
        q, kw, grd_height, counts, bucket, out);
}